// Round 1
// baseline (2549.293 us; speedup 1.0000x reference)
//
#include <hip/hip_runtime.h>
#include <cstdint>
#include <cstddef>

#define BATCH   4
#define NPTS    16384
#define NPOINT  1024
#define NSAMPLE 32
#define CIN     67          // 3 + 64 feature channels
#define R2f     0.04f       // (float)(0.2*0.2)

// ---------------------------------------------------------------------------
// FPS: one block (1024 threads) per batch. Points live in registers
// (16/thread, stride-1024 ownership). Per step: dist min-update + argmax
// (strict '>' keeps lowest index), wave butterfly reduce, cross-wave LDS
// reduce. d2 uses unfused mul/add to match the numpy/XLA reference order.
// ---------------------------------------------------------------------------
__global__ __launch_bounds__(1024) void fps_kernel(
    const float* __restrict__ xyz, float* __restrict__ out_newxyz)
{
  const int b = blockIdx.x;
  const float* base = xyz + (size_t)b * NPTS * 3;
  const int t = threadIdx.x;
  const int lane = t & 63, wid = t >> 6;

  float px[16], py[16], pz[16], dist[16];
#pragma unroll
  for (int j = 0; j < 16; ++j) {
    int p = t + (j << 10);
    px[j] = base[p * 3 + 0];
    py[j] = base[p * 3 + 1];
    pz[j] = base[p * 3 + 2];
    dist[j] = 1e10f;
  }

  __shared__ float s_v[16];
  __shared__ int   s_i[16];
  __shared__ int   s_far;

  int far = 0;
  float cx = base[0], cy = base[1], cz = base[2];

  for (int it = 0; it < NPOINT; ++it) {
    if (t == 0) {                      // record centroid (pre-update far)
      int o = (b * NPOINT + it) * 3;
      out_newxyz[o + 0] = cx;
      out_newxyz[o + 1] = cy;
      out_newxyz[o + 2] = cz;
    }
    float bv = -1.0f; int bi = 0x7fffffff;
#pragma unroll
    for (int j = 0; j < 16; ++j) {
      float dx = __fsub_rn(px[j], cx);
      float dy = __fsub_rn(py[j], cy);
      float dz = __fsub_rn(pz[j], cz);
      float d  = __fadd_rn(__fadd_rn(__fmul_rn(dx, dx), __fmul_rn(dy, dy)),
                           __fmul_rn(dz, dz));
      float nd = fminf(dist[j], d);
      dist[j] = nd;
      bool tk = nd > bv;               // strict > : lowest index wins ties
      bv = tk ? nd : bv;
      bi = tk ? (t + (j << 10)) : bi;
    }
#pragma unroll
    for (int off = 32; off >= 1; off >>= 1) {
      float ov = __shfl_xor(bv, off);
      int   oi = __shfl_xor(bi, off);
      bool tk = (ov > bv) || (ov == bv && oi < bi);
      bv = tk ? ov : bv;
      bi = tk ? oi : bi;
    }
    if (lane == 0) { s_v[wid] = bv; s_i[wid] = bi; }
    __syncthreads();
    if (wid == 0) {
      float v = (lane < 16) ? s_v[lane] : -1.0f;
      int   i = (lane < 16) ? s_i[lane] : 0x7fffffff;
#pragma unroll
      for (int off = 8; off >= 1; off >>= 1) {
        float ov = __shfl_xor(v, off);
        int   oi = __shfl_xor(i, off);
        bool tk = (ov > v) || (ov == v && oi < i);
        v = tk ? ov : v;
        i = tk ? oi : i;
      }
      if (lane == 0) s_far = i;
    }
    __syncthreads();
    far = s_far;                       // safe: next write is after next barrier
    cx = base[far * 3 + 0];            // converged same-address load
    cy = base[far * 3 + 1];
    cz = base[far * 3 + 2];
  }
}

// ---------------------------------------------------------------------------
// features (B,64,N) -> featsT (B,N,64) so per-neighbor gathers are contiguous.
// ---------------------------------------------------------------------------
__global__ __launch_bounds__(256) void transpose_kernel(
    const float* __restrict__ f, float* __restrict__ ft)
{
  __shared__ float tile[64][65];
  int b  = blockIdx.x >> 8;
  int n0 = (blockIdx.x & 255) << 6;
  for (int v = threadIdx.x; v < 64 * 64; v += 256) {
    int c = v >> 6, j = v & 63;
    tile[c][j] = f[((size_t)(b * 64 + c)) * NPTS + n0 + j];
  }
  __syncthreads();
  for (int v = threadIdx.x; v < 64 * 64; v += 256) {
    int j = v >> 6, c = v & 63;
    ft[((size_t)(b * NPTS + n0 + j)) * 64 + c] = tile[c][j];
  }
}

// ---------------------------------------------------------------------------
// Fused ball-query + gather + 3-layer MLP + max-pool.
// Block = 1024 threads, 8 centers/block, grid = 512.
// Phase 0: waves 0..7 each run ball query for one center (ballot ordered
//          compaction, early exit at 32 found, fill with first index).
// Then per center: gather (67x32) -> L1(64) -> L2(64) -> L3(128) -> max_k.
// Weights W1,W2 staged transposed in LDS; W3 read as float4 from global (L1).
// Total static LDS ~63.6 KB (kept under the 64 KB/block limit).
// ---------------------------------------------------------------------------
__global__ __launch_bounds__(1024) void mlp_kernel(
    const float* __restrict__ xyz,
    const float* __restrict__ feats,      // (B,64,N)
    const float* __restrict__ featsT,     // (B,N,64) or null
    const float* __restrict__ nx,         // new_xyz = d_out base (B,1024,3)
    const float* __restrict__ W1, const float* __restrict__ s1, const float* __restrict__ b1,
    const float* __restrict__ W2, const float* __restrict__ s2, const float* __restrict__ b2,
    const float* __restrict__ W3, const float* __restrict__ s3, const float* __restrict__ b3,
    float* __restrict__ outF)             // d_out + 12288, (B,128,1024)
{
  __shared__ float W1t[CIN * 64];     // [i][o]
  __shared__ float W2t[64 * 64];      // [i][o]
  __shared__ float sb[512];           // s1 b1 s2 b2 s3 b3
  __shared__ float xs[CIN * 34];      // [c][k], pad 34 (2-way = free)
  __shared__ float h1[64 * 34];
  __shared__ float h2[64 * 34];
  __shared__ int   hm[128];
  __shared__ int   lid8[8][NSAMPLE];

  const int tid = threadIdx.x;
  const int lane = tid & 63, w = tid >> 6;

  for (int v = tid; v < CIN * 64; v += 1024) {
    int o = v / CIN, i = v - o * CIN;
    W1t[i * 64 + o] = W1[v];
  }
  for (int v = tid; v < 64 * 64; v += 1024) {
    int o = v >> 6, i = v & 63;
    W2t[i * 64 + o] = W2[v];
  }
  if (tid < 64)       sb[tid]       = s1[tid];
  else if (tid < 128) sb[tid]       = b1[tid - 64];
  else if (tid < 192) sb[tid]       = s2[tid - 128];
  else if (tid < 256) sb[tid]       = b2[tid - 192];
  else if (tid < 384) sb[tid]       = s3[tid - 256];
  else if (tid < 512) sb[tid]       = b3[tid - 384];

  // ---- Phase 0: ball query, one wave per center ----
  if (w < 8) {
    int g = (blockIdx.x << 3) + w;
    int b = g >> 10;
    const float* base = xyz + (size_t)b * NPTS * 3;
    float cx = nx[g * 3 + 0], cy = nx[g * 3 + 1], cz = nx[g * 3 + 2];
    int cnt = 0, fidx = -1;
    for (int c0 = 0; c0 < NPTS && cnt < NSAMPLE; c0 += 64) {
      int i = c0 + lane;
      float dx = __fsub_rn(base[i * 3 + 0], cx);
      float dy = __fsub_rn(base[i * 3 + 1], cy);
      float dz = __fsub_rn(base[i * 3 + 2], cz);
      float d2 = __fadd_rn(__fadd_rn(__fmul_rn(dx, dx), __fmul_rn(dy, dy)),
                           __fmul_rn(dz, dz));
      bool pred = d2 < R2f;
      unsigned long long mk = __ballot(pred);
      if (pred) {
        int rank = cnt + __popcll(mk & ((1ull << lane) - 1ull));
        if (rank < NSAMPLE) lid8[w][rank] = i;
        if (rank == 0) fidx = i;
      }
      cnt += __popcll(mk);
    }
#pragma unroll
    for (int off = 32; off >= 1; off >>= 1) {
      int o = __shfl_xor(fidx, off);
      fidx = o > fidx ? o : fidx;
    }
    if (lane >= cnt && lane < NSAMPLE) lid8[w][lane] = fidx;
  }
  __syncthreads();

  // ---- per-center MLP ----
  for (int ci = 0; ci < 8; ++ci) {
    int g = (blockIdx.x << 3) + ci;
    int b = g >> 10, m = g & 1023;

    // gather xs[c][k]  (+ init hm)
    {
      int k = tid >> 5, c0 = tid & 31;
      int id = lid8[ci][k];
      for (int c = c0; c < CIN; c += 32) {
        float val;
        if (c < 3)
          val = __fsub_rn(xyz[((size_t)b * NPTS + id) * 3 + c], nx[g * 3 + c]);
        else if (featsT)
          val = featsT[((size_t)b * NPTS + id) * 64 + (c - 3)];
        else
          val = feats[((size_t)(b * 64 + (c - 3))) * NPTS + id];
        xs[c * 34 + k] = val;
      }
      if (tid < 128) hm[tid] = 0;
    }
    __syncthreads();

    // L1: 67 -> 64
    {
      int oc = tid & 63, k0 = (tid >> 6) << 1;
      float a0 = 0.f, a1 = 0.f;
#pragma unroll 4
      for (int i = 0; i < CIN; ++i) {
        float ww = W1t[i * 64 + oc];
        a0 = fmaf(ww, xs[i * 34 + k0], a0);
        a1 = fmaf(ww, xs[i * 34 + k0 + 1], a1);
      }
      float s = sb[oc], bb = sb[64 + oc];
      h1[oc * 34 + k0]     = fmaxf(fmaf(a0, s, bb), 0.f);
      h1[oc * 34 + k0 + 1] = fmaxf(fmaf(a1, s, bb), 0.f);
    }
    __syncthreads();

    // L2: 64 -> 64
    {
      int oc = tid & 63, k0 = (tid >> 6) << 1;
      float a0 = 0.f, a1 = 0.f;
#pragma unroll 4
      for (int i = 0; i < 64; ++i) {
        float ww = W2t[i * 64 + oc];
        a0 = fmaf(ww, h1[i * 34 + k0], a0);
        a1 = fmaf(ww, h1[i * 34 + k0 + 1], a1);
      }
      float s = sb[128 + oc], bb = sb[192 + oc];
      h2[oc * 34 + k0]     = fmaxf(fmaf(a0, s, bb), 0.f);
      h2[oc * 34 + k0 + 1] = fmaxf(fmaf(a1, s, bb), 0.f);
    }
    __syncthreads();

    // L3: 64 -> 128, fused max over k
    {
      int oc = tid & 127, k0 = (tid >> 7) << 2;
      const float4* W3v = reinterpret_cast<const float4*>(W3);
      float a0 = 0.f, a1 = 0.f, a2 = 0.f, a3 = 0.f;
#pragma unroll 4
      for (int i4 = 0; i4 < 16; ++i4) {
        float4 wv = W3v[oc * 16 + i4];
        const float* hr = &h2[(i4 * 4) * 34 + k0];
        a0 = fmaf(wv.x, hr[0], a0); a1 = fmaf(wv.x, hr[1], a1);
        a2 = fmaf(wv.x, hr[2], a2); a3 = fmaf(wv.x, hr[3], a3);
        hr += 34;
        a0 = fmaf(wv.y, hr[0], a0); a1 = fmaf(wv.y, hr[1], a1);
        a2 = fmaf(wv.y, hr[2], a2); a3 = fmaf(wv.y, hr[3], a3);
        hr += 34;
        a0 = fmaf(wv.z, hr[0], a0); a1 = fmaf(wv.z, hr[1], a1);
        a2 = fmaf(wv.z, hr[2], a2); a3 = fmaf(wv.z, hr[3], a3);
        hr += 34;
        a0 = fmaf(wv.w, hr[0], a0); a1 = fmaf(wv.w, hr[1], a1);
        a2 = fmaf(wv.w, hr[2], a2); a3 = fmaf(wv.w, hr[3], a3);
      }
      float s = sb[256 + oc], bb = sb[384 + oc];
      float v0 = fmaxf(fmaf(a0, s, bb), 0.f);
      float v1 = fmaxf(fmaf(a1, s, bb), 0.f);
      float v2 = fmaxf(fmaf(a2, s, bb), 0.f);
      float v3 = fmaxf(fmaf(a3, s, bb), 0.f);
      float mv = fmaxf(fmaxf(v0, v1), fmaxf(v2, v3));
      atomicMax(&hm[oc], __float_as_int(mv));   // values >= 0: int order == float order
    }
    __syncthreads();

    if (tid < 128)
      outF[(((size_t)b * 128 + tid) << 10) + m] = __int_as_float(hm[tid]);
    __syncthreads();
  }
}

// ---------------------------------------------------------------------------
extern "C" void kernel_launch(void* const* d_in, const int* in_sizes, int n_in,
                              void* d_out, int out_size, void* d_ws, size_t ws_size,
                              hipStream_t stream)
{
  if (n_in < 11) return;
  const float* xyz   = (const float*)d_in[0];
  const float* feats = (const float*)d_in[1];
  const float* W1 = (const float*)d_in[2];
  const float* s1 = (const float*)d_in[3];
  const float* b1 = (const float*)d_in[4];
  const float* W2 = (const float*)d_in[5];
  const float* s2 = (const float*)d_in[6];
  const float* b2 = (const float*)d_in[7];
  const float* W3 = (const float*)d_in[8];
  const float* s3 = (const float*)d_in[9];
  const float* b3 = (const float*)d_in[10];
  float* out = (float*)d_out;

  // optional workspace: transposed features (B,N,64)
  float* featsT = nullptr;
  size_t needT = (size_t)BATCH * NPTS * 64 * sizeof(float);
  if (ws_size >= needT) featsT = (float*)d_ws;

  fps_kernel<<<BATCH, 1024, 0, stream>>>(xyz, out);
  if (featsT) transpose_kernel<<<BATCH * 256, 256, 0, stream>>>(feats, featsT);
  mlp_kernel<<<512, 1024, 0, stream>>>(xyz, feats, featsT, out,
                                       W1, s1, b1, W2, s2, b2, W3, s3, b3,
                                       out + BATCH * NPOINT * 3);
}

// Round 2
// 2261.416 us; speedup vs baseline: 1.1273x; 1.1273x over previous
//
#include <hip/hip_runtime.h>
#include <cstdint>
#include <cstddef>

#define BATCH   4
#define NPTS    16384
#define NPOINT  1024
#define NSAMPLE 32
#define CIN     67          // 3 + 64 feature channels
#define R2f     0.04f       // (float)(0.2*0.2)

#define FPS_T   512
#define FPS_P   32          // 16384 / 512 points per thread

// ---------------------------------------------------------------------------
// DPP-based argmax combine: max value, tie -> lowest index. VALU-pipe only
// (no DS latency). Masked-off rows read old==self -> harmless self-combine.
// ---------------------------------------------------------------------------
template <int CTRL, int RMASK>
__device__ __forceinline__ void amax_dpp(float& v, int& i) {
  int nv = __builtin_amdgcn_update_dpp(__float_as_int(v), __float_as_int(v),
                                       CTRL, RMASK, 0xf, false);
  int ni = __builtin_amdgcn_update_dpp(i, i, CTRL, RMASK, 0xf, false);
  float fv = __int_as_float(nv);
  bool tk = (fv > v) || (fv == v && ni < i);
  v = tk ? fv : v;
  i = tk ? ni : i;
}

// ---------------------------------------------------------------------------
// FPS: one block (512 threads = 8 waves) per batch. 32 points/thread in
// registers. Per step: exact (unfused) d2 + min-update + per-thread argmax
// track, then DPP wave reduce (ror1/2/4/8 + bcast15/31, result lane 63),
// lane63 writes wave result to LDS, ONE barrier, all waves redundantly
// reduce the 8 wave-results with 3 DPP ror levels, readfirstlane -> far,
// scalar centroid load. Double-buffered LDS slots for cross-step WAR safety.
// ---------------------------------------------------------------------------
__global__ __launch_bounds__(512) void fps_kernel(
    const float* __restrict__ xyz, float* __restrict__ out_newxyz)
{
  const int b = blockIdx.x;
  const float* base = xyz + (size_t)b * NPTS * 3;
  const int t = threadIdx.x;
  const int lane = t & 63, w = t >> 6;

  float px[FPS_P], py[FPS_P], pz[FPS_P], dist[FPS_P];
#pragma unroll
  for (int j = 0; j < FPS_P; ++j) {
    int p = t + (j << 9);
    px[j] = base[p * 3 + 0];
    py[j] = base[p * 3 + 1];
    pz[j] = base[p * 3 + 2];
    dist[j] = 1e10f;
  }

  __shared__ float s_wv[2][8];
  __shared__ int   s_wi[2][8];

  float cx = base[0], cy = base[1], cz = base[2];

  for (int it = 0; it < NPOINT; ++it) {
    if (t == 0) {                       // record centroid (pre-update far)
      int o = (b * NPOINT + it) * 3;
      out_newxyz[o + 0] = cx;
      out_newxyz[o + 1] = cy;
      out_newxyz[o + 2] = cz;
    }
    float bv = -1.0f; int bi = 0x7fffffff;
#pragma unroll
    for (int j = 0; j < FPS_P; ++j) {
      float dx = __fsub_rn(px[j], cx);
      float dy = __fsub_rn(py[j], cy);
      float dz = __fsub_rn(pz[j], cz);
      float d  = __fadd_rn(__fadd_rn(__fmul_rn(dx, dx), __fmul_rn(dy, dy)),
                           __fmul_rn(dz, dz));
      float nd = fminf(dist[j], d);
      dist[j] = nd;
      bool tk = nd > bv;                // strict > : lowest index wins ties
      bv = tk ? nd : bv;
      bi = tk ? (t + (j << 9)) : bi;
    }
    // wave argmax via DPP (VALU pipe, low latency); result in lane 63
    amax_dpp<0x121, 0xf>(bv, bi);       // row_ror:1
    amax_dpp<0x122, 0xf>(bv, bi);       // row_ror:2
    amax_dpp<0x124, 0xf>(bv, bi);       // row_ror:4
    amax_dpp<0x128, 0xf>(bv, bi);       // row_ror:8  -> row maxima
    amax_dpp<0x142, 0xa>(bv, bi);       // row_bcast15 -> rows 1,3
    amax_dpp<0x143, 0xc>(bv, bi);       // row_bcast31 -> rows 2,3; lane63 full

    const int par = it & 1;
    if (lane == 63) { s_wv[par][w] = bv; s_wi[par][w] = bi; }
    __syncthreads();

    float gv = s_wv[par][lane & 7];     // same-address broadcast: no conflicts
    int   gi = s_wi[par][lane & 7];
    amax_dpp<0x121, 0xf>(gv, gi);       // combine 8 wave results (period-8)
    amax_dpp<0x122, 0xf>(gv, gi);
    amax_dpp<0x124, 0xf>(gv, gi);

    int far = __builtin_amdgcn_readfirstlane(gi);
    cx = base[far * 3 + 0];             // scalar (uniform) centroid load
    cy = base[far * 3 + 1];
    cz = base[far * 3 + 2];
  }
}

// ---------------------------------------------------------------------------
// features (B,64,N) -> featsT (B,N,64) so per-neighbor gathers are contiguous.
// ---------------------------------------------------------------------------
__global__ __launch_bounds__(256) void transpose_kernel(
    const float* __restrict__ f, float* __restrict__ ft)
{
  __shared__ float tile[64][65];
  int b  = blockIdx.x >> 8;
  int n0 = (blockIdx.x & 255) << 6;
  for (int v = threadIdx.x; v < 64 * 64; v += 256) {
    int c = v >> 6, j = v & 63;
    tile[c][j] = f[((size_t)(b * 64 + c)) * NPTS + n0 + j];
  }
  __syncthreads();
  for (int v = threadIdx.x; v < 64 * 64; v += 256) {
    int j = v >> 6, c = v & 63;
    ft[((size_t)(b * NPTS + n0 + j)) * 64 + c] = tile[c][j];
  }
}

// ---------------------------------------------------------------------------
// Fused ball-query + gather + 3-layer MLP + max-pool. (unchanged this round)
// Block = 1024 threads, 8 centers/block, grid = 512.
// ---------------------------------------------------------------------------
__global__ __launch_bounds__(1024) void mlp_kernel(
    const float* __restrict__ xyz,
    const float* __restrict__ feats,      // (B,64,N)
    const float* __restrict__ featsT,     // (B,N,64) or null
    const float* __restrict__ nx,         // new_xyz = d_out base (B,1024,3)
    const float* __restrict__ W1, const float* __restrict__ s1, const float* __restrict__ b1,
    const float* __restrict__ W2, const float* __restrict__ s2, const float* __restrict__ b2,
    const float* __restrict__ W3, const float* __restrict__ s3, const float* __restrict__ b3,
    float* __restrict__ outF)             // d_out + 12288, (B,128,1024)
{
  __shared__ float W1t[CIN * 64];     // [i][o]
  __shared__ float W2t[64 * 64];      // [i][o]
  __shared__ float sb[512];           // s1 b1 s2 b2 s3 b3
  __shared__ float xs[CIN * 34];      // [c][k], pad 34 (2-way = free)
  __shared__ float h1[64 * 34];
  __shared__ float h2[64 * 34];
  __shared__ int   hm[128];
  __shared__ int   lid8[8][NSAMPLE];

  const int tid = threadIdx.x;
  const int lane = tid & 63, w = tid >> 6;

  for (int v = tid; v < CIN * 64; v += 1024) {
    int o = v / CIN, i = v - o * CIN;
    W1t[i * 64 + o] = W1[v];
  }
  for (int v = tid; v < 64 * 64; v += 1024) {
    int o = v >> 6, i = v & 63;
    W2t[i * 64 + o] = W2[v];
  }
  if (tid < 64)       sb[tid]       = s1[tid];
  else if (tid < 128) sb[tid]       = b1[tid - 64];
  else if (tid < 192) sb[tid]       = s2[tid - 128];
  else if (tid < 256) sb[tid]       = b2[tid - 192];
  else if (tid < 384) sb[tid]       = s3[tid - 256];
  else if (tid < 512) sb[tid]       = b3[tid - 384];

  // ---- Phase 0: ball query, one wave per center ----
  if (w < 8) {
    int g = (blockIdx.x << 3) + w;
    int b = g >> 10;
    const float* base = xyz + (size_t)b * NPTS * 3;
    float cx = nx[g * 3 + 0], cy = nx[g * 3 + 1], cz = nx[g * 3 + 2];
    int cnt = 0, fidx = -1;
    for (int c0 = 0; c0 < NPTS && cnt < NSAMPLE; c0 += 64) {
      int i = c0 + lane;
      float dx = __fsub_rn(base[i * 3 + 0], cx);
      float dy = __fsub_rn(base[i * 3 + 1], cy);
      float dz = __fsub_rn(base[i * 3 + 2], cz);
      float d2 = __fadd_rn(__fadd_rn(__fmul_rn(dx, dx), __fmul_rn(dy, dy)),
                           __fmul_rn(dz, dz));
      bool pred = d2 < R2f;
      unsigned long long mk = __ballot(pred);
      if (pred) {
        int rank = cnt + __popcll(mk & ((1ull << lane) - 1ull));
        if (rank < NSAMPLE) lid8[w][rank] = i;
        if (rank == 0) fidx = i;
      }
      cnt += __popcll(mk);
    }
#pragma unroll
    for (int off = 32; off >= 1; off >>= 1) {
      int o = __shfl_xor(fidx, off);
      fidx = o > fidx ? o : fidx;
    }
    if (lane >= cnt && lane < NSAMPLE) lid8[w][lane] = fidx;
  }
  __syncthreads();

  // ---- per-center MLP ----
  for (int ci = 0; ci < 8; ++ci) {
    int g = (blockIdx.x << 3) + ci;
    int b = g >> 10, m = g & 1023;

    // gather xs[c][k]  (+ init hm)
    {
      int k = tid >> 5, c0 = tid & 31;
      int id = lid8[ci][k];
      for (int c = c0; c < CIN; c += 32) {
        float val;
        if (c < 3)
          val = __fsub_rn(xyz[((size_t)b * NPTS + id) * 3 + c], nx[g * 3 + c]);
        else if (featsT)
          val = featsT[((size_t)b * NPTS + id) * 64 + (c - 3)];
        else
          val = feats[((size_t)(b * 64 + (c - 3))) * NPTS + id];
        xs[c * 34 + k] = val;
      }
      if (tid < 128) hm[tid] = 0;
    }
    __syncthreads();

    // L1: 67 -> 64
    {
      int oc = tid & 63, k0 = (tid >> 6) << 1;
      float a0 = 0.f, a1 = 0.f;
#pragma unroll 4
      for (int i = 0; i < CIN; ++i) {
        float ww = W1t[i * 64 + oc];
        a0 = fmaf(ww, xs[i * 34 + k0], a0);
        a1 = fmaf(ww, xs[i * 34 + k0 + 1], a1);
      }
      float s = sb[oc], bb = sb[64 + oc];
      h1[oc * 34 + k0]     = fmaxf(fmaf(a0, s, bb), 0.f);
      h1[oc * 34 + k0 + 1] = fmaxf(fmaf(a1, s, bb), 0.f);
    }
    __syncthreads();

    // L2: 64 -> 64
    {
      int oc = tid & 63, k0 = (tid >> 6) << 1;
      float a0 = 0.f, a1 = 0.f;
#pragma unroll 4
      for (int i = 0; i < 64; ++i) {
        float ww = W2t[i * 64 + oc];
        a0 = fmaf(ww, h1[i * 34 + k0], a0);
        a1 = fmaf(ww, h1[i * 34 + k0 + 1], a1);
      }
      float s = sb[128 + oc], bb = sb[192 + oc];
      h2[oc * 34 + k0]     = fmaxf(fmaf(a0, s, bb), 0.f);
      h2[oc * 34 + k0 + 1] = fmaxf(fmaf(a1, s, bb), 0.f);
    }
    __syncthreads();

    // L3: 64 -> 128, fused max over k
    {
      int oc = tid & 127, k0 = (tid >> 7) << 2;
      const float4* W3v = reinterpret_cast<const float4*>(W3);
      float a0 = 0.f, a1 = 0.f, a2 = 0.f, a3 = 0.f;
#pragma unroll 4
      for (int i4 = 0; i4 < 16; ++i4) {
        float4 wv = W3v[oc * 16 + i4];
        const float* hr = &h2[(i4 * 4) * 34 + k0];
        a0 = fmaf(wv.x, hr[0], a0); a1 = fmaf(wv.x, hr[1], a1);
        a2 = fmaf(wv.x, hr[2], a2); a3 = fmaf(wv.x, hr[3], a3);
        hr += 34;
        a0 = fmaf(wv.y, hr[0], a0); a1 = fmaf(wv.y, hr[1], a1);
        a2 = fmaf(wv.y, hr[2], a2); a3 = fmaf(wv.y, hr[3], a3);
        hr += 34;
        a0 = fmaf(wv.z, hr[0], a0); a1 = fmaf(wv.z, hr[1], a1);
        a2 = fmaf(wv.z, hr[2], a2); a3 = fmaf(wv.z, hr[3], a3);
        hr += 34;
        a0 = fmaf(wv.w, hr[0], a0); a1 = fmaf(wv.w, hr[1], a1);
        a2 = fmaf(wv.w, hr[2], a2); a3 = fmaf(wv.w, hr[3], a3);
      }
      float s = sb[256 + oc], bb = sb[384 + oc];
      float v0 = fmaxf(fmaf(a0, s, bb), 0.f);
      float v1 = fmaxf(fmaf(a1, s, bb), 0.f);
      float v2 = fmaxf(fmaf(a2, s, bb), 0.f);
      float v3 = fmaxf(fmaf(a3, s, bb), 0.f);
      float mv = fmaxf(fmaxf(v0, v1), fmaxf(v2, v3));
      atomicMax(&hm[oc], __float_as_int(mv));   // values >= 0: int order == float order
    }
    __syncthreads();

    if (tid < 128)
      outF[(((size_t)b * 128 + tid) << 10) + m] = __int_as_float(hm[tid]);
    __syncthreads();
  }
}

// ---------------------------------------------------------------------------
extern "C" void kernel_launch(void* const* d_in, const int* in_sizes, int n_in,
                              void* d_out, int out_size, void* d_ws, size_t ws_size,
                              hipStream_t stream)
{
  if (n_in < 11) return;
  const float* xyz   = (const float*)d_in[0];
  const float* feats = (const float*)d_in[1];
  const float* W1 = (const float*)d_in[2];
  const float* s1 = (const float*)d_in[3];
  const float* b1 = (const float*)d_in[4];
  const float* W2 = (const float*)d_in[5];
  const float* s2 = (const float*)d_in[6];
  const float* b2 = (const float*)d_in[7];
  const float* W3 = (const float*)d_in[8];
  const float* s3 = (const float*)d_in[9];
  const float* b3 = (const float*)d_in[10];
  float* out = (float*)d_out;

  // optional workspace: transposed features (B,N,64)
  float* featsT = nullptr;
  size_t needT = (size_t)BATCH * NPTS * 64 * sizeof(float);
  if (ws_size >= needT) featsT = (float*)d_ws;

  fps_kernel<<<BATCH, FPS_T, 0, stream>>>(xyz, out);
  if (featsT) transpose_kernel<<<BATCH * 256, 256, 0, stream>>>(feats, featsT);
  mlp_kernel<<<512, 1024, 0, stream>>>(xyz, feats, featsT, out,
                                       W1, s1, b1, W2, s2, b2, W3, s3, b3,
                                       out + BATCH * NPOINT * 3);
}

// Round 3
// 2254.987 us; speedup vs baseline: 1.1305x; 1.0029x over previous
//
#include <hip/hip_runtime.h>
#include <cstdint>
#include <cstddef>

#define BATCH   4
#define NPTS    16384
#define NPOINT  1024
#define NSAMPLE 32
#define CIN     67          // 3 + 64 feature channels
#define R2f     0.04f       // (float)(0.2*0.2)

#define FPS_T   512
#define FPS_P   32          // 16384 / 512 points per thread

// ---------------------------------------------------------------------------
// DPP-based argmax combine: max value, tie -> lowest index. VALU-pipe only
// (no DS latency). Masked-off rows read old==self -> harmless self-combine.
// ---------------------------------------------------------------------------
template <int CTRL, int RMASK>
__device__ __forceinline__ void amax_dpp(float& v, int& i) {
  int nv = __builtin_amdgcn_update_dpp(__float_as_int(v), __float_as_int(v),
                                       CTRL, RMASK, 0xf, false);
  int ni = __builtin_amdgcn_update_dpp(i, i, CTRL, RMASK, 0xf, false);
  float fv = __int_as_float(nv);
  bool tk = (fv > v) || (fv == v && ni < i);
  v = tk ? fv : v;
  i = tk ? ni : i;
}

// ---------------------------------------------------------------------------
// FPS: one block (512 threads = 8 waves) per batch. 32 points/thread held in
// REGISTERS: launch_bounds(512,2) -> 256-VGPR cap so the 128-float point
// state does NOT spill (R2's 84-VGPR allocation spilled dist[] to scratch and
// cost ~2.5x). Per step: exact unfused d2 + min-update + argmax track, DPP
// wave reduce, one barrier, redundant 8-entry cross-wave DPP reduce,
// readfirstlane -> scalar centroid load.
// ---------------------------------------------------------------------------
__global__ __launch_bounds__(FPS_T, 2) void fps_kernel(
    const float* __restrict__ xyz, float* __restrict__ out_newxyz)
{
  const int b = blockIdx.x;
  const float* base = xyz + (size_t)b * NPTS * 3;
  const int t = threadIdx.x;
  const int lane = t & 63, w = t >> 6;

  float px[FPS_P], py[FPS_P], pz[FPS_P], dist[FPS_P];
#pragma unroll
  for (int j = 0; j < FPS_P; ++j) {
    int p = t + (j << 9);
    px[j] = base[p * 3 + 0];
    py[j] = base[p * 3 + 1];
    pz[j] = base[p * 3 + 2];
    dist[j] = 1e10f;
  }

  __shared__ float s_wv[2][8];
  __shared__ int   s_wi[2][8];

  float cx = base[0], cy = base[1], cz = base[2];

  for (int it = 0; it < NPOINT; ++it) {
    if (t == 0) {                       // record centroid (pre-update far)
      int o = (b * NPOINT + it) * 3;
      out_newxyz[o + 0] = cx;
      out_newxyz[o + 1] = cy;
      out_newxyz[o + 2] = cz;
    }
    float bv = -1.0f; int bi = 0x7fffffff;
#pragma unroll
    for (int j = 0; j < FPS_P; ++j) {
      float dx = __fsub_rn(px[j], cx);
      float dy = __fsub_rn(py[j], cy);
      float dz = __fsub_rn(pz[j], cz);
      float d  = __fadd_rn(__fadd_rn(__fmul_rn(dx, dx), __fmul_rn(dy, dy)),
                           __fmul_rn(dz, dz));
      float nd = fminf(dist[j], d);
      dist[j] = nd;
      bool tk = nd > bv;                // strict > : lowest index wins ties
      bv = tk ? nd : bv;
      bi = tk ? (t + (j << 9)) : bi;
    }
    // wave argmax via DPP (VALU pipe, low latency); result in lane 63
    amax_dpp<0x121, 0xf>(bv, bi);       // row_ror:1
    amax_dpp<0x122, 0xf>(bv, bi);       // row_ror:2
    amax_dpp<0x124, 0xf>(bv, bi);       // row_ror:4
    amax_dpp<0x128, 0xf>(bv, bi);       // row_ror:8  -> row maxima
    amax_dpp<0x142, 0xa>(bv, bi);       // row_bcast15 -> rows 1,3
    amax_dpp<0x143, 0xc>(bv, bi);       // row_bcast31 -> rows 2,3; lane63 full

    const int par = it & 1;
    if (lane == 63) { s_wv[par][w] = bv; s_wi[par][w] = bi; }
    __syncthreads();

    float gv = s_wv[par][lane & 7];     // same-address broadcast: no conflicts
    int   gi = s_wi[par][lane & 7];
    amax_dpp<0x121, 0xf>(gv, gi);       // combine 8 wave results (period-8)
    amax_dpp<0x122, 0xf>(gv, gi);
    amax_dpp<0x124, 0xf>(gv, gi);

    int far = __builtin_amdgcn_readfirstlane(gi);
    cx = base[far * 3 + 0];             // scalar (uniform) centroid load
    cy = base[far * 3 + 1];
    cz = base[far * 3 + 2];
  }
}

// ---------------------------------------------------------------------------
// features (B,64,N) -> featsT (B,N,64) so per-neighbor gathers are contiguous.
// ---------------------------------------------------------------------------
__global__ __launch_bounds__(256) void transpose_kernel(
    const float* __restrict__ f, float* __restrict__ ft)
{
  __shared__ float tile[64][65];
  int b  = blockIdx.x >> 8;
  int n0 = (blockIdx.x & 255) << 6;
  for (int v = threadIdx.x; v < 64 * 64; v += 256) {
    int c = v >> 6, j = v & 63;
    tile[c][j] = f[((size_t)(b * 64 + c)) * NPTS + n0 + j];
  }
  __syncthreads();
  for (int v = threadIdx.x; v < 64 * 64; v += 256) {
    int j = v >> 6, c = v & 63;
    ft[((size_t)(b * NPTS + n0 + j)) * 64 + c] = tile[c][j];
  }
}

// ---------------------------------------------------------------------------
// Fused ball-query + gather + 3-layer MLP + max-pool. (unchanged this round)
// Block = 1024 threads, 8 centers/block, grid = 512.
// ---------------------------------------------------------------------------
__global__ __launch_bounds__(1024) void mlp_kernel(
    const float* __restrict__ xyz,
    const float* __restrict__ feats,      // (B,64,N)
    const float* __restrict__ featsT,     // (B,N,64) or null
    const float* __restrict__ nx,         // new_xyz = d_out base (B,1024,3)
    const float* __restrict__ W1, const float* __restrict__ s1, const float* __restrict__ b1,
    const float* __restrict__ W2, const float* __restrict__ s2, const float* __restrict__ b2,
    const float* __restrict__ W3, const float* __restrict__ s3, const float* __restrict__ b3,
    float* __restrict__ outF)             // d_out + 12288, (B,128,1024)
{
  __shared__ float W1t[CIN * 64];     // [i][o]
  __shared__ float W2t[64 * 64];      // [i][o]
  __shared__ float sb[512];           // s1 b1 s2 b2 s3 b3
  __shared__ float xs[CIN * 34];      // [c][k], pad 34 (2-way = free)
  __shared__ float h1[64 * 34];
  __shared__ float h2[64 * 34];
  __shared__ int   hm[128];
  __shared__ int   lid8[8][NSAMPLE];

  const int tid = threadIdx.x;
  const int lane = tid & 63, w = tid >> 6;

  for (int v = tid; v < CIN * 64; v += 1024) {
    int o = v / CIN, i = v - o * CIN;
    W1t[i * 64 + o] = W1[v];
  }
  for (int v = tid; v < 64 * 64; v += 1024) {
    int o = v >> 6, i = v & 63;
    W2t[i * 64 + o] = W2[v];
  }
  if (tid < 64)       sb[tid]       = s1[tid];
  else if (tid < 128) sb[tid]       = b1[tid - 64];
  else if (tid < 192) sb[tid]       = s2[tid - 128];
  else if (tid < 256) sb[tid]       = b2[tid - 192];
  else if (tid < 384) sb[tid]       = s3[tid - 256];
  else if (tid < 512) sb[tid]       = b3[tid - 384];

  // ---- Phase 0: ball query, one wave per center ----
  if (w < 8) {
    int g = (blockIdx.x << 3) + w;
    int b = g >> 10;
    const float* base = xyz + (size_t)b * NPTS * 3;
    float cx = nx[g * 3 + 0], cy = nx[g * 3 + 1], cz = nx[g * 3 + 2];
    int cnt = 0, fidx = -1;
    for (int c0 = 0; c0 < NPTS && cnt < NSAMPLE; c0 += 64) {
      int i = c0 + lane;
      float dx = __fsub_rn(base[i * 3 + 0], cx);
      float dy = __fsub_rn(base[i * 3 + 1], cy);
      float dz = __fsub_rn(base[i * 3 + 2], cz);
      float d2 = __fadd_rn(__fadd_rn(__fmul_rn(dx, dx), __fmul_rn(dy, dy)),
                           __fmul_rn(dz, dz));
      bool pred = d2 < R2f;
      unsigned long long mk = __ballot(pred);
      if (pred) {
        int rank = cnt + __popcll(mk & ((1ull << lane) - 1ull));
        if (rank < NSAMPLE) lid8[w][rank] = i;
        if (rank == 0) fidx = i;
      }
      cnt += __popcll(mk);
    }
#pragma unroll
    for (int off = 32; off >= 1; off >>= 1) {
      int o = __shfl_xor(fidx, off);
      fidx = o > fidx ? o : fidx;
    }
    if (lane >= cnt && lane < NSAMPLE) lid8[w][lane] = fidx;
  }
  __syncthreads();

  // ---- per-center MLP ----
  for (int ci = 0; ci < 8; ++ci) {
    int g = (blockIdx.x << 3) + ci;
    int b = g >> 10, m = g & 1023;

    // gather xs[c][k]  (+ init hm)
    {
      int k = tid >> 5, c0 = tid & 31;
      int id = lid8[ci][k];
      for (int c = c0; c < CIN; c += 32) {
        float val;
        if (c < 3)
          val = __fsub_rn(xyz[((size_t)b * NPTS + id) * 3 + c], nx[g * 3 + c]);
        else if (featsT)
          val = featsT[((size_t)b * NPTS + id) * 64 + (c - 3)];
        else
          val = feats[((size_t)(b * 64 + (c - 3))) * NPTS + id];
        xs[c * 34 + k] = val;
      }
      if (tid < 128) hm[tid] = 0;
    }
    __syncthreads();

    // L1: 67 -> 64
    {
      int oc = tid & 63, k0 = (tid >> 6) << 1;
      float a0 = 0.f, a1 = 0.f;
#pragma unroll 4
      for (int i = 0; i < CIN; ++i) {
        float ww = W1t[i * 64 + oc];
        a0 = fmaf(ww, xs[i * 34 + k0], a0);
        a1 = fmaf(ww, xs[i * 34 + k0 + 1], a1);
      }
      float s = sb[oc], bb = sb[64 + oc];
      h1[oc * 34 + k0]     = fmaxf(fmaf(a0, s, bb), 0.f);
      h1[oc * 34 + k0 + 1] = fmaxf(fmaf(a1, s, bb), 0.f);
    }
    __syncthreads();

    // L2: 64 -> 64
    {
      int oc = tid & 63, k0 = (tid >> 6) << 1;
      float a0 = 0.f, a1 = 0.f;
#pragma unroll 4
      for (int i = 0; i < 64; ++i) {
        float ww = W2t[i * 64 + oc];
        a0 = fmaf(ww, h1[i * 34 + k0], a0);
        a1 = fmaf(ww, h1[i * 34 + k0 + 1], a1);
      }
      float s = sb[128 + oc], bb = sb[192 + oc];
      h2[oc * 34 + k0]     = fmaxf(fmaf(a0, s, bb), 0.f);
      h2[oc * 34 + k0 + 1] = fmaxf(fmaf(a1, s, bb), 0.f);
    }
    __syncthreads();

    // L3: 64 -> 128, fused max over k
    {
      int oc = tid & 127, k0 = (tid >> 7) << 2;
      const float4* W3v = reinterpret_cast<const float4*>(W3);
      float a0 = 0.f, a1 = 0.f, a2 = 0.f, a3 = 0.f;
#pragma unroll 4
      for (int i4 = 0; i4 < 16; ++i4) {
        float4 wv = W3v[oc * 16 + i4];
        const float* hr = &h2[(i4 * 4) * 34 + k0];
        a0 = fmaf(wv.x, hr[0], a0); a1 = fmaf(wv.x, hr[1], a1);
        a2 = fmaf(wv.x, hr[2], a2); a3 = fmaf(wv.x, hr[3], a3);
        hr += 34;
        a0 = fmaf(wv.y, hr[0], a0); a1 = fmaf(wv.y, hr[1], a1);
        a2 = fmaf(wv.y, hr[2], a2); a3 = fmaf(wv.y, hr[3], a3);
        hr += 34;
        a0 = fmaf(wv.z, hr[0], a0); a1 = fmaf(wv.z, hr[1], a1);
        a2 = fmaf(wv.z, hr[2], a2); a3 = fmaf(wv.z, hr[3], a3);
        hr += 34;
        a0 = fmaf(wv.w, hr[0], a0); a1 = fmaf(wv.w, hr[1], a1);
        a2 = fmaf(wv.w, hr[2], a2); a3 = fmaf(wv.w, hr[3], a3);
      }
      float s = sb[256 + oc], bb = sb[384 + oc];
      float v0 = fmaxf(fmaf(a0, s, bb), 0.f);
      float v1 = fmaxf(fmaf(a1, s, bb), 0.f);
      float v2 = fmaxf(fmaf(a2, s, bb), 0.f);
      float v3 = fmaxf(fmaf(a3, s, bb), 0.f);
      float mv = fmaxf(fmaxf(v0, v1), fmaxf(v2, v3));
      atomicMax(&hm[oc], __float_as_int(mv));   // values >= 0: int order == float order
    }
    __syncthreads();

    if (tid < 128)
      outF[(((size_t)b * 128 + tid) << 10) + m] = __int_as_float(hm[tid]);
    __syncthreads();
  }
}

// ---------------------------------------------------------------------------
extern "C" void kernel_launch(void* const* d_in, const int* in_sizes, int n_in,
                              void* d_out, int out_size, void* d_ws, size_t ws_size,
                              hipStream_t stream)
{
  if (n_in < 11) return;
  const float* xyz   = (const float*)d_in[0];
  const float* feats = (const float*)d_in[1];
  const float* W1 = (const float*)d_in[2];
  const float* s1 = (const float*)d_in[3];
  const float* b1 = (const float*)d_in[4];
  const float* W2 = (const float*)d_in[5];
  const float* s2 = (const float*)d_in[6];
  const float* b2 = (const float*)d_in[7];
  const float* W3 = (const float*)d_in[8];
  const float* s3 = (const float*)d_in[9];
  const float* b3 = (const float*)d_in[10];
  float* out = (float*)d_out;

  // optional workspace: transposed features (B,N,64)
  float* featsT = nullptr;
  size_t needT = (size_t)BATCH * NPTS * 64 * sizeof(float);
  if (ws_size >= needT) featsT = (float*)d_ws;

  fps_kernel<<<BATCH, FPS_T, 0, stream>>>(xyz, out);
  if (featsT) transpose_kernel<<<BATCH * 256, 256, 0, stream>>>(feats, featsT);
  mlp_kernel<<<512, 1024, 0, stream>>>(xyz, feats, featsT, out,
                                       W1, s1, b1, W2, s2, b2, W3, s3, b3,
                                       out + BATCH * NPOINT * 3);
}

// Round 4
// 2252.936 us; speedup vs baseline: 1.1315x; 1.0009x over previous
//
#include <hip/hip_runtime.h>
#include <cstdint>
#include <cstddef>

#define BATCH   4
#define NPTS    16384
#define NPOINT  1024
#define NSAMPLE 32
#define CIN     67          // 3 + 64 feature channels
#define R2f     0.04f       // (float)(0.2*0.2)

#define FPS_T   512
#define FPS_P   32          // 16384 / 512 points per thread

#define RPT32(M) M(0)M(1)M(2)M(3)M(4)M(5)M(6)M(7)M(8)M(9)M(10)M(11)M(12)M(13)M(14)M(15) \
                 M(16)M(17)M(18)M(19)M(20)M(21)M(22)M(23)M(24)M(25)M(26)M(27)M(28)M(29)M(30)M(31)

// ---------------------------------------------------------------------------
// DPP-based argmax combine: max value, tie -> lowest index. VALU-pipe only.
// ---------------------------------------------------------------------------
template <int CTRL, int RMASK>
__device__ __forceinline__ void amax_dpp(float& v, int& i) {
  int nv = __builtin_amdgcn_update_dpp(__float_as_int(v), __float_as_int(v),
                                       CTRL, RMASK, 0xf, false);
  int ni = __builtin_amdgcn_update_dpp(i, i, CTRL, RMASK, 0xf, false);
  float fv = __int_as_float(nv);
  bool tk = (fv > v) || (fv == v && ni < i);
  v = tk ? fv : v;
  i = tk ? ni : i;
}

// ---------------------------------------------------------------------------
// FPS: one block (512 threads = 8 waves) per batch. 32 points/thread as
// NAMED SCALARS (macro-expanded) so SROA/RA must keep them in registers;
// amdgpu_waves_per_eu(2,2) pins the allocator budget to 256 regs/wave
// (R2/R3's array form allocated only 84 arch VGPRs and shuffled the state
// through AGPR copies -> ~2x VALU inflation). Per-thread argmax tracks the
// LOCAL point index i (inline-const select operand); global = (i<<9)+t.
// ---------------------------------------------------------------------------
__global__ void __attribute__((amdgpu_flat_work_group_size(FPS_T, FPS_T),
                               amdgpu_waves_per_eu(2, 2)))
fps_kernel(const float* __restrict__ xyz, float* __restrict__ out_newxyz)
{
  const int b = blockIdx.x;
  const float* base = xyz + (size_t)b * NPTS * 3;
  const int t = threadIdx.x;
  const int lane = t & 63, w = t >> 6;

#define DECLV(i) float px##i, py##i, pz##i, dd##i;
  RPT32(DECLV)
#undef DECLV
#define LOADV(i) { const float* p = base + (size_t)(((i) << 9) + t) * 3; \
                   px##i = p[0]; py##i = p[1]; pz##i = p[2]; dd##i = 1e10f; }
  RPT32(LOADV)
#undef LOADV

  __shared__ float s_wv[2][8];
  __shared__ int   s_wi[2][8];

  float cx = base[0], cy = base[1], cz = base[2];

  for (int it = 0; it < NPOINT; ++it) {
    if (t == 0) {                       // record centroid (pre-update far)
      int o = (b * NPOINT + it) * 3;
      out_newxyz[o + 0] = cx;
      out_newxyz[o + 1] = cy;
      out_newxyz[o + 2] = cz;
    }
    float bv = -1.0f; int bl = 0;
#define STEPV(i) { \
    float dx = __fsub_rn(px##i, cx); \
    float dy = __fsub_rn(py##i, cy); \
    float dz = __fsub_rn(pz##i, cz); \
    float d2 = __fadd_rn(__fadd_rn(__fmul_rn(dx, dx), __fmul_rn(dy, dy)), \
                         __fmul_rn(dz, dz)); \
    float nd = fminf(dd##i, d2); dd##i = nd; \
    bool tk = nd > bv;  /* strict > : lowest local index wins ties */ \
    bv = tk ? nd : bv; \
    bl = tk ? (i) : bl; }
    RPT32(STEPV)
#undef STEPV
    int bi = (bl << 9) + t;             // global point index

    // wave argmax via DPP (VALU pipe); result valid in lane 63
    amax_dpp<0x121, 0xf>(bv, bi);       // row_ror:1
    amax_dpp<0x122, 0xf>(bv, bi);       // row_ror:2
    amax_dpp<0x124, 0xf>(bv, bi);       // row_ror:4
    amax_dpp<0x128, 0xf>(bv, bi);       // row_ror:8  -> row maxima
    amax_dpp<0x142, 0xa>(bv, bi);       // row_bcast15 -> rows 1,3
    amax_dpp<0x143, 0xc>(bv, bi);       // row_bcast31 -> lane63 has full wave

    const int par = it & 1;
    if (lane == 63) { s_wv[par][w] = bv; s_wi[par][w] = bi; }
    __syncthreads();

    float gv = s_wv[par][lane & 7];     // same-address broadcast: no conflicts
    int   gi = s_wi[par][lane & 7];
    amax_dpp<0x121, 0xf>(gv, gi);       // combine 8 wave results (period-8)
    amax_dpp<0x122, 0xf>(gv, gi);
    amax_dpp<0x124, 0xf>(gv, gi);

    int far = __builtin_amdgcn_readfirstlane(gi);
    cx = base[far * 3 + 0];             // uniform centroid load
    cy = base[far * 3 + 1];
    cz = base[far * 3 + 2];
  }
}

// ---------------------------------------------------------------------------
// features (B,64,N) -> featsT (B,N,64) so per-neighbor gathers are contiguous.
// ---------------------------------------------------------------------------
__global__ __launch_bounds__(256) void transpose_kernel(
    const float* __restrict__ f, float* __restrict__ ft)
{
  __shared__ float tile[64][65];
  int b  = blockIdx.x >> 8;
  int n0 = (blockIdx.x & 255) << 6;
  for (int v = threadIdx.x; v < 64 * 64; v += 256) {
    int c = v >> 6, j = v & 63;
    tile[c][j] = f[((size_t)(b * 64 + c)) * NPTS + n0 + j];
  }
  __syncthreads();
  for (int v = threadIdx.x; v < 64 * 64; v += 256) {
    int j = v >> 6, c = v & 63;
    ft[((size_t)(b * NPTS + n0 + j)) * 64 + c] = tile[c][j];
  }
}

// ---------------------------------------------------------------------------
// Fused ball-query + gather + 3-layer MLP + max-pool. (unchanged this round)
// Block = 1024 threads, 8 centers/block, grid = 512.
// ---------------------------------------------------------------------------
__global__ __launch_bounds__(1024) void mlp_kernel(
    const float* __restrict__ xyz,
    const float* __restrict__ feats,      // (B,64,N)
    const float* __restrict__ featsT,     // (B,N,64) or null
    const float* __restrict__ nx,         // new_xyz = d_out base (B,1024,3)
    const float* __restrict__ W1, const float* __restrict__ s1, const float* __restrict__ b1,
    const float* __restrict__ W2, const float* __restrict__ s2, const float* __restrict__ b2,
    const float* __restrict__ W3, const float* __restrict__ s3, const float* __restrict__ b3,
    float* __restrict__ outF)             // d_out + 12288, (B,128,1024)
{
  __shared__ float W1t[CIN * 64];     // [i][o]
  __shared__ float W2t[64 * 64];      // [i][o]
  __shared__ float sb[512];           // s1 b1 s2 b2 s3 b3
  __shared__ float xs[CIN * 34];      // [c][k], pad 34 (2-way = free)
  __shared__ float h1[64 * 34];
  __shared__ float h2[64 * 34];
  __shared__ int   hm[128];
  __shared__ int   lid8[8][NSAMPLE];

  const int tid = threadIdx.x;
  const int lane = tid & 63, w = tid >> 6;

  for (int v = tid; v < CIN * 64; v += 1024) {
    int o = v / CIN, i = v - o * CIN;
    W1t[i * 64 + o] = W1[v];
  }
  for (int v = tid; v < 64 * 64; v += 1024) {
    int o = v >> 6, i = v & 63;
    W2t[i * 64 + o] = W2[v];
  }
  if (tid < 64)       sb[tid]       = s1[tid];
  else if (tid < 128) sb[tid]       = b1[tid - 64];
  else if (tid < 192) sb[tid]       = s2[tid - 128];
  else if (tid < 256) sb[tid]       = b2[tid - 192];
  else if (tid < 384) sb[tid]       = s3[tid - 256];
  else if (tid < 512) sb[tid]       = b3[tid - 384];

  // ---- Phase 0: ball query, one wave per center ----
  if (w < 8) {
    int g = (blockIdx.x << 3) + w;
    int b = g >> 10;
    const float* base = xyz + (size_t)b * NPTS * 3;
    float cx = nx[g * 3 + 0], cy = nx[g * 3 + 1], cz = nx[g * 3 + 2];
    int cnt = 0, fidx = -1;
    for (int c0 = 0; c0 < NPTS && cnt < NSAMPLE; c0 += 64) {
      int i = c0 + lane;
      float dx = __fsub_rn(base[i * 3 + 0], cx);
      float dy = __fsub_rn(base[i * 3 + 1], cy);
      float dz = __fsub_rn(base[i * 3 + 2], cz);
      float d2 = __fadd_rn(__fadd_rn(__fmul_rn(dx, dx), __fmul_rn(dy, dy)),
                           __fmul_rn(dz, dz));
      bool pred = d2 < R2f;
      unsigned long long mk = __ballot(pred);
      if (pred) {
        int rank = cnt + __popcll(mk & ((1ull << lane) - 1ull));
        if (rank < NSAMPLE) lid8[w][rank] = i;
        if (rank == 0) fidx = i;
      }
      cnt += __popcll(mk);
    }
#pragma unroll
    for (int off = 32; off >= 1; off >>= 1) {
      int o = __shfl_xor(fidx, off);
      fidx = o > fidx ? o : fidx;
    }
    if (lane >= cnt && lane < NSAMPLE) lid8[w][lane] = fidx;
  }
  __syncthreads();

  // ---- per-center MLP ----
  for (int ci = 0; ci < 8; ++ci) {
    int g = (blockIdx.x << 3) + ci;
    int b = g >> 10, m = g & 1023;

    // gather xs[c][k]  (+ init hm)
    {
      int k = tid >> 5, c0 = tid & 31;
      int id = lid8[ci][k];
      for (int c = c0; c < CIN; c += 32) {
        float val;
        if (c < 3)
          val = __fsub_rn(xyz[((size_t)b * NPTS + id) * 3 + c], nx[g * 3 + c]);
        else if (featsT)
          val = featsT[((size_t)b * NPTS + id) * 64 + (c - 3)];
        else
          val = feats[((size_t)(b * 64 + (c - 3))) * NPTS + id];
        xs[c * 34 + k] = val;
      }
      if (tid < 128) hm[tid] = 0;
    }
    __syncthreads();

    // L1: 67 -> 64
    {
      int oc = tid & 63, k0 = (tid >> 6) << 1;
      float a0 = 0.f, a1 = 0.f;
#pragma unroll 4
      for (int i = 0; i < CIN; ++i) {
        float ww = W1t[i * 64 + oc];
        a0 = fmaf(ww, xs[i * 34 + k0], a0);
        a1 = fmaf(ww, xs[i * 34 + k0 + 1], a1);
      }
      float s = sb[oc], bb = sb[64 + oc];
      h1[oc * 34 + k0]     = fmaxf(fmaf(a0, s, bb), 0.f);
      h1[oc * 34 + k0 + 1] = fmaxf(fmaf(a1, s, bb), 0.f);
    }
    __syncthreads();

    // L2: 64 -> 64
    {
      int oc = tid & 63, k0 = (tid >> 6) << 1;
      float a0 = 0.f, a1 = 0.f;
#pragma unroll 4
      for (int i = 0; i < 64; ++i) {
        float ww = W2t[i * 64 + oc];
        a0 = fmaf(ww, h1[i * 34 + k0], a0);
        a1 = fmaf(ww, h1[i * 34 + k0 + 1], a1);
      }
      float s = sb[128 + oc], bb = sb[192 + oc];
      h2[oc * 34 + k0]     = fmaxf(fmaf(a0, s, bb), 0.f);
      h2[oc * 34 + k0 + 1] = fmaxf(fmaf(a1, s, bb), 0.f);
    }
    __syncthreads();

    // L3: 64 -> 128, fused max over k
    {
      int oc = tid & 127, k0 = (tid >> 7) << 2;
      const float4* W3v = reinterpret_cast<const float4*>(W3);
      float a0 = 0.f, a1 = 0.f, a2 = 0.f, a3 = 0.f;
#pragma unroll 4
      for (int i4 = 0; i4 < 16; ++i4) {
        float4 wv = W3v[oc * 16 + i4];
        const float* hr = &h2[(i4 * 4) * 34 + k0];
        a0 = fmaf(wv.x, hr[0], a0); a1 = fmaf(wv.x, hr[1], a1);
        a2 = fmaf(wv.x, hr[2], a2); a3 = fmaf(wv.x, hr[3], a3);
        hr += 34;
        a0 = fmaf(wv.y, hr[0], a0); a1 = fmaf(wv.y, hr[1], a1);
        a2 = fmaf(wv.y, hr[2], a2); a3 = fmaf(wv.y, hr[3], a3);
        hr += 34;
        a0 = fmaf(wv.z, hr[0], a0); a1 = fmaf(wv.z, hr[1], a1);
        a2 = fmaf(wv.z, hr[2], a2); a3 = fmaf(wv.z, hr[3], a3);
        hr += 34;
        a0 = fmaf(wv.w, hr[0], a0); a1 = fmaf(wv.w, hr[1], a1);
        a2 = fmaf(wv.w, hr[2], a2); a3 = fmaf(wv.w, hr[3], a3);
      }
      float s = sb[256 + oc], bb = sb[384 + oc];
      float v0 = fmaxf(fmaf(a0, s, bb), 0.f);
      float v1 = fmaxf(fmaf(a1, s, bb), 0.f);
      float v2 = fmaxf(fmaf(a2, s, bb), 0.f);
      float v3 = fmaxf(fmaf(a3, s, bb), 0.f);
      float mv = fmaxf(fmaxf(v0, v1), fmaxf(v2, v3));
      atomicMax(&hm[oc], __float_as_int(mv));   // values >= 0: int order == float order
    }
    __syncthreads();

    if (tid < 128)
      outF[(((size_t)b * 128 + tid) << 10) + m] = __int_as_float(hm[tid]);
    __syncthreads();
  }
}

// ---------------------------------------------------------------------------
extern "C" void kernel_launch(void* const* d_in, const int* in_sizes, int n_in,
                              void* d_out, int out_size, void* d_ws, size_t ws_size,
                              hipStream_t stream)
{
  if (n_in < 11) return;
  const float* xyz   = (const float*)d_in[0];
  const float* feats = (const float*)d_in[1];
  const float* W1 = (const float*)d_in[2];
  const float* s1 = (const float*)d_in[3];
  const float* b1 = (const float*)d_in[4];
  const float* W2 = (const float*)d_in[5];
  const float* s2 = (const float*)d_in[6];
  const float* b2 = (const float*)d_in[7];
  const float* W3 = (const float*)d_in[8];
  const float* s3 = (const float*)d_in[9];
  const float* b3 = (const float*)d_in[10];
  float* out = (float*)d_out;

  // optional workspace: transposed features (B,N,64)
  float* featsT = nullptr;
  size_t needT = (size_t)BATCH * NPTS * 64 * sizeof(float);
  if (ws_size >= needT) featsT = (float*)d_ws;

  fps_kernel<<<BATCH, FPS_T, 0, stream>>>(xyz, out);
  if (featsT) transpose_kernel<<<BATCH * 256, 256, 0, stream>>>(feats, featsT);
  mlp_kernel<<<512, 1024, 0, stream>>>(xyz, feats, featsT, out,
                                       W1, s1, b1, W2, s2, b2, W3, s3, b3,
                                       out + BATCH * NPOINT * 3);
}